// Round 1
// baseline (79.485 us; speedup 1.0000x reference)
//
#include <hip/hip_runtime.h>
#include <stdint.h>

// Problem: B=8192, IN_F=1024, OUT_F=4096, pool 2x2 over 64x64 -> 1024 pooled feats.
// pooled[b,o] = x[b,:] . Wp[o,:] + biasp[o] + 0.25*(y[b,n0]+y[b,n0+1]+y[b,n0+64]+y[b,n0+65])
//   where o = p*32+q, n0 = 128p+2q, Wp[o,:] = mean of 4 W rows, biasp = mean of 4 bias.
// out[b*1024+o] = pooled[b,o] / mean(pooled)

#define MDIM 8192
#define KDIM 1024
#define NP   1024
#define OUTN (8192 * 1024)

typedef __bf16 bf16x8 __attribute__((ext_vector_type(8)));
typedef float f32x4 __attribute__((ext_vector_type(4)));

__device__ __forceinline__ unsigned f2bf(float f) {
  union { float f; unsigned u; } v; v.f = f;
  unsigned r = v.u + 0x7fffu + ((v.u >> 16) & 1u);  // RNE
  return r >> 16;
}

__device__ __forceinline__ void gload_lds16(const void* g, void* l) {
  __builtin_amdgcn_global_load_lds(
      (const __attribute__((address_space(1))) void*)g,
      (__attribute__((address_space(3))) void*)l, 16, 0, 0);
}

// ---- kernel 1: x fp32 -> bf16 ----
__global__ void k_conv_x(const float* __restrict__ x, unsigned short* __restrict__ xb) {
  int i = blockIdx.x * 256 + threadIdx.x;  // 8 elems per thread
  const float4* x4 = (const float4*)x;
  float4 a = x4[i * 2], b = x4[i * 2 + 1];
  uint4 o;
  o.x = f2bf(a.x) | (f2bf(a.y) << 16);
  o.y = f2bf(a.z) | (f2bf(a.w) << 16);
  o.z = f2bf(b.x) | (f2bf(b.y) << 16);
  o.w = f2bf(b.z) | (f2bf(b.w) << 16);
  ((uint4*)xb)[i] = o;
}

// ---- kernel 2: pool W rows -> Wp bf16 [1024][1024], pool bias ----
__global__ void k_prep_w(const float* __restrict__ W, const float* __restrict__ bias,
                         unsigned short* __restrict__ wp, float* __restrict__ biasp) {
  int o = blockIdx.x;  // pooled feature index
  int r0 = ((o >> 5) << 7) + ((o & 31) << 1);
  int t = threadIdx.x;  // 256 threads x 4 k-elems
  const float4* W4 = (const float4*)W;
  float4 w0 = W4[(r0) * 256 + t];
  float4 w1 = W4[(r0 + 1) * 256 + t];
  float4 w2 = W4[(r0 + 64) * 256 + t];
  float4 w3 = W4[(r0 + 65) * 256 + t];
  float ax = 0.25f * (w0.x + w1.x + w2.x + w3.x);
  float ay = 0.25f * (w0.y + w1.y + w2.y + w3.y);
  float az = 0.25f * (w0.z + w1.z + w2.z + w3.z);
  float aw = 0.25f * (w0.w + w1.w + w2.w + w3.w);
  uint2 pk;
  pk.x = f2bf(ax) | (f2bf(ay) << 16);
  pk.y = f2bf(az) | (f2bf(aw) << 16);
  ((uint2*)wp)[o * 256 + t] = pk;
  if (t == 0)
    biasp[o] = 0.25f * (bias[r0] + bias[r0 + 1] + bias[r0 + 64] + bias[r0 + 65]);
}

// ---- kernel 3: GEMM 8192x1024x1024 bf16 MFMA, epilogue pools y + partial sums ----
#define BM 128
#define BN 128
#define BK 64

__global__ __launch_bounds__(256) void k_gemm(
    const unsigned short* __restrict__ xb, const unsigned short* __restrict__ wp,
    const float* __restrict__ biasp, const float* __restrict__ y,
    float* __restrict__ out, float* __restrict__ partials) {
  __shared__ unsigned short As[BM * BK];
  __shared__ unsigned short Bs[BN * BK];
  __shared__ float wsum[4];

  int bid = blockIdx.x;
  // XCD swizzle: nwg=512, divisible by 8 -> simple bijective form
  int wg = (bid & 7) * 64 + (bid >> 3);
  int bm0 = (wg >> 3) * BM;
  int bn0 = (wg & 7) * BN;

  int tid = threadIdx.x;
  int lane = tid & 63;
  int wid = tid >> 6;
  int wr = wid >> 1, wc = wid & 1;  // wave tile: 64x64 at (wr*64, wc*64)

  f32x4 acc[4][4];
#pragma unroll
  for (int i = 0; i < 4; i++)
#pragma unroll
    for (int j = 0; j < 4; j++) acc[i][j] = (f32x4)0.0f;

  // staging geometry: per wave, 4 calls each for A and B; call i covers rows
  // [wid*32 + i*8, +8) of the tile, lane covers (lane>>3) row, (lane&7)*8 col.
  int srow = wid * 32 + (lane >> 3);
  int scol = (lane & 7) * 8;
  const unsigned short* aSrc = xb + (size_t)(bm0 + srow) * KDIM + scol;
  const unsigned short* bSrc = wp + (size_t)(bn0 + srow) * KDIM + scol;

  for (int ks = 0; ks < KDIM / BK; ++ks) {
    int k0 = ks * BK;
#pragma unroll
    for (int i = 0; i < 4; ++i) {
      gload_lds16(aSrc + i * 8 * KDIM + k0, (char*)As + wid * 4096 + i * 1024);
      gload_lds16(bSrc + i * 8 * KDIM + k0, (char*)Bs + wid * 4096 + i * 1024);
    }
    __syncthreads();
#pragma unroll
    for (int kk = 0; kk < 2; ++kk) {
      bf16x8 af[4], bfr[4];
#pragma unroll
      for (int mi = 0; mi < 4; ++mi)
        af[mi] = *(const bf16x8*)&As[(wr * 64 + mi * 16 + (lane & 15)) * BK + kk * 32 + (lane >> 4) * 8];
#pragma unroll
      for (int ni = 0; ni < 4; ++ni)
        bfr[ni] = *(const bf16x8*)&Bs[(wc * 64 + ni * 16 + (lane & 15)) * BK + kk * 32 + (lane >> 4) * 8];
#pragma unroll
      for (int mi = 0; mi < 4; ++mi)
#pragma unroll
        for (int ni = 0; ni < 4; ++ni)
          acc[mi][ni] = __builtin_amdgcn_mfma_f32_16x16x32_bf16(af[mi], bfr[ni], acc[mi][ni], 0, 0, 0);
    }
    __syncthreads();
  }

  // epilogue: add pooled bias + pooled y, write, accumulate block sum
  const float2* y2 = (const float2*)y;
  float tsum = 0.f;
  int r_l = (lane >> 4) * 4;
  int c_l = lane & 15;
#pragma unroll
  for (int mi = 0; mi < 4; ++mi) {
#pragma unroll
    for (int ni = 0; ni < 4; ++ni) {
      int col = bn0 + wc * 64 + ni * 16 + c_l;  // pooled feature o
      float bp = biasp[col];
      int y2base = ((col >> 5) << 6) + (col & 31);
#pragma unroll
      for (int j = 0; j < 4; ++j) {
        int row = bm0 + wr * 64 + mi * 16 + r_l + j;  // batch b
        float2 u = y2[(size_t)row * 2048 + y2base];
        float2 v = y2[(size_t)row * 2048 + y2base + 32];
        float val = acc[mi][ni][j] + bp + 0.25f * (u.x + u.y + v.x + v.y);
        out[(size_t)row * NP + col] = val;
        tsum += val;
      }
    }
  }
#pragma unroll
  for (int off = 32; off > 0; off >>= 1) tsum += __shfl_down(tsum, off);
  if (lane == 0) wsum[wid] = tsum;
  __syncthreads();
  if (tid == 0) partials[bid] = wsum[0] + wsum[1] + wsum[2] + wsum[3];
}

// ---- kernel 4: reduce 512 partials -> 1/mean ----
__global__ void k_reduce(const float* __restrict__ partials, float* __restrict__ invm) {
  __shared__ float s[256];
  int t = threadIdx.x;
  s[t] = partials[t] + partials[t + 256];
  __syncthreads();
  for (int off = 128; off > 0; off >>= 1) {
    if (t < off) s[t] += s[t + off];
    __syncthreads();
  }
  if (t == 0) invm[0] = 8388608.0f / s[0];
}

// ---- kernel 5: scale d_out in place ----
__global__ void k_norm(float* __restrict__ out, const float* __restrict__ invm) {
  int i = blockIdx.x * 256 + threadIdx.x;
  float inv = invm[0];
  float4* o4 = (float4*)out;
  float4 v = o4[i];
  v.x *= inv; v.y *= inv; v.z *= inv; v.w *= inv;
  o4[i] = v;
}

extern "C" void kernel_launch(void* const* d_in, const int* in_sizes, int n_in,
                              void* d_out, int out_size, void* d_ws, size_t ws_size,
                              hipStream_t stream) {
  (void)in_sizes; (void)n_in; (void)out_size; (void)ws_size;
  const float* x = (const float*)d_in[0];
  const float* y = (const float*)d_in[1];
  const float* W = (const float*)d_in[2];
  const float* bias = (const float*)d_in[3];
  float* out = (float*)d_out;

  char* ws = (char*)d_ws;
  unsigned short* xb = (unsigned short*)(ws);                    // 16 MiB
  unsigned short* wp = (unsigned short*)(ws + 16777216);         // 2 MiB
  float* biasp = (float*)(ws + 16777216 + 2097152);              // 4 KiB
  float* partials = (float*)(ws + 16777216 + 2097152 + 4096);    // 2 KiB
  float* invm = (float*)(ws + 16777216 + 2097152 + 4096 + 2048); // 4 B

  hipLaunchKernelGGL(k_conv_x, dim3(4096), dim3(256), 0, stream, x, xb);
  hipLaunchKernelGGL(k_prep_w, dim3(1024), dim3(256), 0, stream, W, bias, wp, biasp);
  hipLaunchKernelGGL(k_gemm, dim3(512), dim3(256), 0, stream, xb, wp, biasp, y, out, partials);
  hipLaunchKernelGGL(k_reduce, dim3(1), dim3(256), 0, stream, partials, invm);
  hipLaunchKernelGGL(k_norm, dim3(8192), dim3(256), 0, stream, out, invm);
}

// Round 2
// 67.751 us; speedup vs baseline: 1.1732x; 1.1732x over previous
//
#include <hip/hip_runtime.h>
#include <stdint.h>

// pooled[b,o] = x[b,:] . Wp[o,:] + biasp[o] + 0.25*(y[b,n0]+y[b,n0+1]+y[b,n0+64]+y[b,n0+65])
//   o = p*32+q, n0 = 128p+2q; Wp = 2x2-pooled W rows. out = pooled / mean(pooled).

#define KDIM 1024
#define NP   1024
#define BM 128
#define BN 128
#define BK 64

typedef __bf16 bf16x8 __attribute__((ext_vector_type(8)));
typedef float f32x4 __attribute__((ext_vector_type(4)));

__device__ __forceinline__ unsigned f2bf(float f) {
  union { float f; unsigned u; } v; v.f = f;
  unsigned r = v.u + 0x7fffu + ((v.u >> 16) & 1u);  // RNE
  return r >> 16;
}

__device__ __forceinline__ void gload_lds16(const void* g, void* l) {
  __builtin_amdgcn_global_load_lds(
      (const __attribute__((address_space(1))) void*)g,
      (__attribute__((address_space(3))) void*)l, 16, 0, 0);
}

// ---- kernel 1 (merged prep): x fp32->bf16 (blocks 0..4095), pool W+bias (4096..5119) ----
__global__ void k_prep(const float* __restrict__ x, const float* __restrict__ W,
                       const float* __restrict__ bias,
                       unsigned short* __restrict__ xb, unsigned short* __restrict__ wp,
                       float* __restrict__ biasp) {
  int b = blockIdx.x;
  int t = threadIdx.x;
  if (b < 4096) {
    int i = b * 256 + t;  // 8 elems per thread
    const float4* x4 = (const float4*)x;
    float4 a = x4[i * 2], c = x4[i * 2 + 1];
    uint4 o;
    o.x = f2bf(a.x) | (f2bf(a.y) << 16);
    o.y = f2bf(a.z) | (f2bf(a.w) << 16);
    o.z = f2bf(c.x) | (f2bf(c.y) << 16);
    o.w = f2bf(c.z) | (f2bf(c.w) << 16);
    ((uint4*)xb)[i] = o;
  } else {
    int o = b - 4096;  // pooled feature index
    int r0 = ((o >> 5) << 7) + ((o & 31) << 1);
    const float4* W4 = (const float4*)W;
    float4 w0 = W4[(r0) * 256 + t];
    float4 w1 = W4[(r0 + 1) * 256 + t];
    float4 w2 = W4[(r0 + 64) * 256 + t];
    float4 w3 = W4[(r0 + 65) * 256 + t];
    float ax = 0.25f * (w0.x + w1.x + w2.x + w3.x);
    float ay = 0.25f * (w0.y + w1.y + w2.y + w3.y);
    float az = 0.25f * (w0.z + w1.z + w2.z + w3.z);
    float aw = 0.25f * (w0.w + w1.w + w2.w + w3.w);
    uint2 pk;
    pk.x = f2bf(ax) | (f2bf(ay) << 16);
    pk.y = f2bf(az) | (f2bf(aw) << 16);
    ((uint2*)wp)[o * 256 + t] = pk;
    if (t == 0)
      biasp[o] = 0.25f * (bias[r0] + bias[r0 + 1] + bias[r0 + 64] + bias[r0 + 65]);
  }
}

// ---- kernel 2: GEMM 8192x1024x1024 bf16 MFMA; dbuf LDS + counted vmcnt + XOR swizzle ----
__global__ __launch_bounds__(256) void k_gemm(
    const unsigned short* __restrict__ xb, const unsigned short* __restrict__ wp,
    const float* __restrict__ biasp, const float* __restrict__ y,
    float* __restrict__ out, float* __restrict__ partials) {
  // layout: buf in {0,1}: As(buf)=smem+buf*32768 (16KB), Bs(buf)=+16384
  __shared__ char smem[65536];

  int bid = blockIdx.x;
  // XCD swizzle: nwg=512 = 8*64, bijective
  int wg = (bid & 7) * 64 + (bid >> 3);
  int bm0 = (wg >> 3) * BM;
  int bn0 = (wg & 7) * BN;

  int tid = threadIdx.x;
  int lane = tid & 63;
  int wid = tid >> 6;
  int wr = wid >> 1, wc = wid & 1;  // wave tile 64x64

  f32x4 acc[4][4];
#pragma unroll
  for (int i = 0; i < 4; i++)
#pragma unroll
    for (int j = 0; j < 4; j++) acc[i][j] = (f32x4)0.0f;

  // staging: wave covers rows [wid*32, +32) over 4 calls of 8 rows each.
  // LDS dest is linear; SOURCE column chunk is pre-swizzled by (lane&7)^(lane>>3)
  // so that a swizzled READ sees the correct data (both-sides involution).
  int srow = wid * 32 + (lane >> 3);
  int scol = (((lane & 7) ^ (lane >> 3)) << 3);
  const unsigned short* aSrc = xb + (size_t)(bm0 + srow) * KDIM + scol;
  const unsigned short* bSrc = wp + (size_t)(bn0 + srow) * KDIM + scol;
  int ldsOff = wid * 4096;

  // read addressing: row r = {wr|wc}*64 + mi*16 + (lane&15); byte col =
  // (kk*64 + (lane>>4)*16) ^ ((r&7)<<4); r&7 == lane&7 for all frags.
  int rbase = (lane & 15) * 128;
  int xorv = (lane & 7) << 4;
  int cb0 = (((lane >> 4) * 16)) ^ xorv;
  int cb1 = ((64 + (lane >> 4) * 16)) ^ xorv;

#define STAGE(buf, ks)                                                         \
  {                                                                            \
    int k0 = (ks) * BK;                                                        \
    char* ab = smem + (buf) * 32768 + ldsOff;                                  \
    char* bb = smem + (buf) * 32768 + 16384 + ldsOff;                          \
    _Pragma("unroll")                                                          \
    for (int i = 0; i < 4; ++i) {                                              \
      gload_lds16(aSrc + (size_t)i * 8 * KDIM + k0, ab + i * 1024);            \
      gload_lds16(bSrc + (size_t)i * 8 * KDIM + k0, bb + i * 1024);            \
    }                                                                          \
  }

  STAGE(0, 0);
  for (int ks = 0; ks < 16; ++ks) {
    int cur = ks & 1;
    if (ks < 15) {
      STAGE(cur ^ 1, ks + 1);
      asm volatile("s_waitcnt vmcnt(8)" ::: "memory");
    } else {
      asm volatile("s_waitcnt vmcnt(0)" ::: "memory");
    }
    __builtin_amdgcn_s_barrier();
    asm volatile("" ::: "memory");
    const char* Ab = smem + cur * 32768;
    const char* Bb = Ab + 16384;
#pragma unroll
    for (int kk = 0; kk < 2; ++kk) {
      int cb = kk ? cb1 : cb0;
      bf16x8 af[4], bfr[4];
#pragma unroll
      for (int mi = 0; mi < 4; ++mi)
        af[mi] = *(const bf16x8*)(Ab + (wr * 64 + mi * 16) * 128 + rbase + cb);
#pragma unroll
      for (int ni = 0; ni < 4; ++ni)
        bfr[ni] = *(const bf16x8*)(Bb + (wc * 64 + ni * 16) * 128 + rbase + cb);
#pragma unroll
      for (int mi = 0; mi < 4; ++mi)
#pragma unroll
        for (int ni = 0; ni < 4; ++ni)
          acc[mi][ni] = __builtin_amdgcn_mfma_f32_16x16x32_bf16(af[mi], bfr[ni], acc[mi][ni], 0, 0, 0);
    }
    asm volatile("" ::: "memory");
    __builtin_amdgcn_s_barrier();
  }

  // epilogue: add pooled bias + pooled y, write, accumulate block sum
  const float2* y2 = (const float2*)y;
  float tsum = 0.f;
  int r_l = (lane >> 4) * 4;
  int c_l = lane & 15;
#pragma unroll
  for (int mi = 0; mi < 4; ++mi) {
#pragma unroll
    for (int ni = 0; ni < 4; ++ni) {
      int col = bn0 + wc * 64 + ni * 16 + c_l;  // pooled feature o
      float bp = biasp[col];
      int y2base = ((col >> 5) << 6) + (col & 31);
#pragma unroll
      for (int j = 0; j < 4; ++j) {
        int row = bm0 + wr * 64 + mi * 16 + r_l + j;  // batch b
        float2 u = y2[(size_t)row * 2048 + y2base];
        float2 v = y2[(size_t)row * 2048 + y2base + 32];
        float val = acc[mi][ni][j] + bp + 0.25f * (u.x + u.y + v.x + v.y);
        out[(size_t)row * NP + col] = val;
        tsum += val;
      }
    }
  }
#pragma unroll
  for (int off = 32; off > 0; off >>= 1) tsum += __shfl_down(tsum, off);
  float* ws4 = (float*)smem;
  __syncthreads();
  if (lane == 0) ws4[wid] = tsum;
  __syncthreads();
  if (tid == 0) partials[bid] = ws4[0] + ws4[1] + ws4[2] + ws4[3];
}

// ---- kernel 3: reduce 512 partials -> 1/mean ----
__global__ void k_reduce(const float* __restrict__ partials, float* __restrict__ invm) {
  __shared__ float s[256];
  int t = threadIdx.x;
  s[t] = partials[t] + partials[t + 256];
  __syncthreads();
  for (int off = 128; off > 0; off >>= 1) {
    if (t < off) s[t] += s[t + off];
    __syncthreads();
  }
  if (t == 0) invm[0] = 8388608.0f / s[0];
}

// ---- kernel 4: scale d_out in place ----
__global__ void k_norm(float* __restrict__ out, const float* __restrict__ invm) {
  int i = blockIdx.x * 256 + threadIdx.x;
  float inv = invm[0];
  float4* o4 = (float4*)out;
  float4 v = o4[i];
  v.x *= inv; v.y *= inv; v.z *= inv; v.w *= inv;
  o4[i] = v;
}

extern "C" void kernel_launch(void* const* d_in, const int* in_sizes, int n_in,
                              void* d_out, int out_size, void* d_ws, size_t ws_size,
                              hipStream_t stream) {
  (void)in_sizes; (void)n_in; (void)out_size; (void)ws_size;
  const float* x = (const float*)d_in[0];
  const float* y = (const float*)d_in[1];
  const float* W = (const float*)d_in[2];
  const float* bias = (const float*)d_in[3];
  float* out = (float*)d_out;

  char* ws = (char*)d_ws;
  unsigned short* xb = (unsigned short*)(ws);                    // 16 MiB
  unsigned short* wp = (unsigned short*)(ws + 16777216);         // 2 MiB
  float* biasp = (float*)(ws + 16777216 + 2097152);              // 4 KiB
  float* partials = (float*)(ws + 16777216 + 2097152 + 4096);    // 2 KiB
  float* invm = (float*)(ws + 16777216 + 2097152 + 4096 + 2048); // 4 B

  hipLaunchKernelGGL(k_prep, dim3(5120), dim3(256), 0, stream, x, W, bias, xb, wp, biasp);
  hipLaunchKernelGGL(k_gemm, dim3(512), dim3(256), 0, stream, xb, wp, biasp, y, out, partials);
  hipLaunchKernelGGL(k_reduce, dim3(1), dim3(256), 0, stream, partials, invm);
  hipLaunchKernelGGL(k_norm, dim3(8192), dim3(256), 0, stream, out, invm);
}